// Round 7
// baseline (538.226 us; speedup 1.0000x reference)
//
#include <hip/hip_runtime.h>
#include <stdint.h>
#include <stddef.h>

// B=4,N=64 -> BN=256 batches; L=256; IN=128; H=512; heads=8; hd=64.
// Inputs may be bf16 OR float32 (harness-dependent) -> runtime-detected flag.
// All internal compute: bf16 MFMA + fp32 accumulate.

typedef __attribute__((ext_vector_type(8))) short short8;
typedef __attribute__((ext_vector_type(4))) float f32x4;

#define AS1(p) ((const __attribute__((address_space(1))) void*)(p))
#define AS3(p) ((__attribute__((address_space(3))) void*)(p))

__device__ __forceinline__ float b2f(uint16_t u) {
    union { uint32_t i; float f; } x; x.i = ((uint32_t)u) << 16; return x.f;
}
__device__ __forceinline__ uint16_t f2b(float f) {
    union { float f; uint32_t i; } x; x.f = f;
    uint32_t r = x.i + 0x7fffu + ((x.i >> 16) & 1u);  // RNE
    return (uint16_t)(r >> 16);
}

// ---------------------------------------------------------------------------
// Dtype sniffer: bf16 N(0,1) data -> exponent field in ~[110,135] (outliers
// ~0%). float32 data read as uint16: even elements are f32 low-mantissa
// halves -> ~uniform exponent bits -> ~42% outliers. flag=1 means float32.
// ---------------------------------------------------------------------------
__global__ void k_detect(const uint16_t* __restrict__ q, int* __restrict__ flag) {
    const int t = threadIdx.x;
    int cnt = 0;
    for (int i = 0; i < 32; ++i) {
        const int e = (q[t * 32 + i] >> 7) & 0xff;
        cnt += (e < 110) | (e > 135);
    }
#pragma unroll
    for (int m = 1; m < 64; m <<= 1) cnt += __shfl_xor(cnt, m, 64);
    if (t == 0) *flag = (cnt > 256) ? 1 : 0;
}

__device__ __forceinline__ uint16_t rd_any(const void* p, size_t idx, int isf) {
    return isf ? f2b(((const float*)p)[idx]) : ((const uint16_t*)p)[idx];
}

// ---------------------------------------------------------------------------
// Transpose weights W (K x 512) -> Wt (512 x K) bf16, so GEMM B-fragments
// read 16B contiguous along k. Tiny, L2-resident.
// ---------------------------------------------------------------------------
__global__ void k_transpose(const void* __restrict__ Wq, const void* __restrict__ Wk,
                            const void* __restrict__ Wv, const void* __restrict__ Wo,
                            uint16_t* __restrict__ wtq, uint16_t* __restrict__ wtk,
                            uint16_t* __restrict__ wtv, uint16_t* __restrict__ wto,
                            const int* __restrict__ flag) {
    const int isf = *flag;
    const int z = blockIdx.y;
    const int t = blockIdx.x * 256 + threadIdx.x;
    if (z < 3) {
        if (t >= 128 * 512) return;
        const void* W = (z == 0) ? Wq : (z == 1) ? Wk : Wv;
        uint16_t* o = (z == 0) ? wtq : (z == 1) ? wtk : wtv;
        const int k = t & 127, n = t >> 7;
        o[t] = rd_any(W, (size_t)k * 512 + n, isf);   // o[n*128+k] = W[k][n]
    } else {
        const int k = t & 511, n = t >> 9;
        wto[t] = rd_any(Wo, (size_t)k * 512 + n, isf);
    }
}

// ---------------------------------------------------------------------------
// GEMM v7: DIRECT-FRAGMENT, barrier-free. C(Mx512)=A(MxK)@Wt(512xK)^T + bias.
// 128x128 tile, 4 waves 2x2, 16x16x32 bf16 MFMA.
//
// Round-6 counters proved the LDS-staged form is latency-bound, not BW-bound:
// FETCH dropped 188->50 MB (XCD swizzle) yet dur didn't move — the serial
// stage->vmcnt(0)->compute barrier drain IS the cost. But both operands are
// cache-resident by construction (W: <=512KB, every block reads it; A-tiles:
// read 4x back-to-back on the SAME XCD thanks to the swizzle), and the MFMA
// fragment pattern is directly loadable from global with full 64B-line
// consumption (quads 0/1 cover k0..15 of rows 0..15 in one instruction).
// So: NO LDS staging, NO barriers. Per-lane fragment loads from L2, f32
// converted inline. Per-kt ILP (16-24 outstanding loads) + TLP hides ~200cy
// L2 latency under ~160cy MFMA. #pragma unroll 1 on kt keeps live fragments
// to one kt (af32+bf32+acc64 ~ 160 VGPR < 256 cap — R2/R4 spill rule).
// LDS: only the wave-private epilogue bounce (no barrier needed: wave-local
// DS ordering, same pattern as attn's epilogue).
// ---------------------------------------------------------------------------
template<int KITERS>
__device__ __forceinline__ void gemm_dev(const void* __restrict__ Av, const int lda,
                                         const uint16_t* __restrict__ Wt,
                                         const void* __restrict__ biasv,
                                         void* __restrict__ Cv,
                                         const int m0, const int n0,
                                         const int isf_a, const int isf_bias, const int isf_c) {
    __shared__ __align__(16) uint16_t Obs[4 * 4096];  // 32 KB epilogue bounce
    const int tid = threadIdx.x;
    const int lane = tid & 63, w = tid >> 6;
    const int wr = w >> 1, wc = w & 1;
    const int quad = lane >> 4, cl = lane & 15;

    f32x4 acc[4][4];
#pragma unroll
    for (int i = 0; i < 4; ++i)
#pragma unroll
        for (int j = 0; j < 4; ++j) acc[i][j] = (f32x4){0.f, 0.f, 0.f, 0.f};

    const int arow = m0 + wr * 64 + cl;   // + mt*16
    const int brow = n0 + wc * 64 + cl;   // + nt*16

#pragma unroll 1
    for (int kt = 0; kt < KITERS; ++kt) {
        const int k0 = kt * 64 + quad * 8;
        short8 af[4][2], bf[4][2];
        if (!isf_a) {
#pragma unroll
            for (int ks = 0; ks < 2; ++ks)
#pragma unroll
                for (int mt = 0; mt < 4; ++mt)
                    af[mt][ks] = *(const short8*)((const uint16_t*)Av +
                                 (size_t)(arow + mt * 16) * lda + k0 + ks * 32);
        } else {
            f32x4 u[4][2][2];
#pragma unroll
            for (int ks = 0; ks < 2; ++ks)
#pragma unroll
                for (int mt = 0; mt < 4; ++mt) {
                    const float* p = (const float*)Av + (size_t)(arow + mt * 16) * lda + k0 + ks * 32;
                    u[mt][ks][0] = *(const f32x4*)p;
                    u[mt][ks][1] = *(const f32x4*)(p + 4);
                }
#pragma unroll
            for (int ks = 0; ks < 2; ++ks)
#pragma unroll
                for (int mt = 0; mt < 4; ++mt) {
                    short8 tv;
#pragma unroll
                    for (int j = 0; j < 4; ++j) {
                        tv[j] = (short)f2b(u[mt][ks][0][j]);
                        tv[4 + j] = (short)f2b(u[mt][ks][1][j]);
                    }
                    af[mt][ks] = tv;
                }
        }
#pragma unroll
        for (int ks = 0; ks < 2; ++ks)
#pragma unroll
            for (int nt = 0; nt < 4; ++nt)
                bf[nt][ks] = *(const short8*)(Wt + (size_t)(brow + nt * 16) * lda + k0 + ks * 32);
#pragma unroll
        for (int ks = 0; ks < 2; ++ks)
#pragma unroll
            for (int mt = 0; mt < 4; ++mt)
#pragma unroll
                for (int nt = 0; nt < 4; ++nt)
                    acc[mt][nt] = __builtin_amdgcn_mfma_f32_16x16x32_bf16(af[mt][ks], bf[nt][ks], acc[mt][nt], 0, 0, 0);
    }

    // Epilogue. C/D layout (m89-verified): col=lane&15, row=quad*4+reg.
    if (!isf_c) {
        // bf16 C: bounce through wave-private LDS (no barrier: wave-local),
        // then full 64B-line short8 stores.
        uint16_t* const Ob = Obs + w * 4096;  // 64x64, chunk-XOR swizzled
#pragma unroll
        for (int nt = 0; nt < 4; ++nt) {
            const int col = nt * 16 + cl;  // wave-local col
            const float bv = isf_bias ? ((const float*)biasv)[n0 + wc * 64 + col]
                                      : b2f(((const uint16_t*)biasv)[n0 + wc * 64 + col]);
#pragma unroll
            for (int mt = 0; mt < 4; ++mt)
#pragma unroll
                for (int r = 0; r < 4; ++r) {
                    const int row = mt * 16 + quad * 4 + r;  // wave-local row
                    Ob[row * 64 + (((col >> 3) ^ (row & 7)) & 7) * 8 + (col & 7)] =
                        f2b(acc[mt][nt][r] + bv);
                }
        }
#pragma unroll
        for (int g = 0; g < 8; ++g) {
            const int row = g * 8 + (lane >> 3);
            const int c = lane & 7;
            const short8 ov = *(const short8*)(Ob + row * 64 + ((c ^ (row & 7)) & 7) * 8);
            *(short8*)((uint16_t*)Cv + (size_t)(m0 + wr * 64 + row) * 512 + n0 + wc * 64 + c * 8) = ov;
        }
    } else {
#pragma unroll
        for (int nt = 0; nt < 4; ++nt) {
            const int col = n0 + wc * 64 + nt * 16 + cl;
            const float bv = isf_bias ? ((const float*)biasv)[col] : b2f(((const uint16_t*)biasv)[col]);
#pragma unroll
            for (int mt = 0; mt < 4; ++mt)
#pragma unroll
                for (int r = 0; r < 4; ++r) {
                    const int rowg = m0 + wr * 64 + mt * 16 + quad * 4 + r;
                    ((float*)Cv)[(size_t)rowg * 512 + col] = acc[mt][nt][r] + bv;
                }
        }
    }
}

// Grid (4,512,3): 6144 blocks. Bijective XCD remap (6144%8==0, chunk=768):
// nid=(id&7)*768+(id>>3); n-tile fastest. The 4 n-siblings of one A-tile are
// consecutive nid -> same XCD (R6-verified: FETCH 188->50 MB).
__global__ __launch_bounds__(256, 2) void k_gemm_proj(
    const void* qi, const void* ki, const void* vi,
    const uint16_t* wtq, const uint16_t* wtk, const uint16_t* wtv,
    const void* bq, const void* bk, const void* bv,
    uint16_t* cq, uint16_t* ck, uint16_t* cv, const int* flag) {
    const int isf = *flag;
    const int id = blockIdx.x + (blockIdx.y << 2) + (blockIdx.z << 11);
    const int nid = (id & 7) * 768 + (id >> 3);
    const int z = nid >> 11;
    const int y = (nid >> 2) & 511;   // m-tile
    const int x = nid & 3;            // n-tile (fast)
    const void* A = (z == 0) ? qi : (z == 1) ? ki : vi;
    const uint16_t* W = (z == 0) ? wtq : (z == 1) ? wtk : wtv;
    const void* B = (z == 0) ? bq : (z == 1) ? bk : bv;
    uint16_t* C = (z == 0) ? cq : (z == 1) ? ck : cv;
    gemm_dev<2>(A, 128, W, B, C, y * 128, x * 128, isf, isf, 0);  // C bf16
}

// Grid (4,512): 2048 blocks, chunk=256.
__global__ __launch_bounds__(256, 2) void k_gemm_out(
    const uint16_t* __restrict__ A, const uint16_t* __restrict__ Wt,
    const void* __restrict__ bias, void* __restrict__ C, const int* flag) {
    const int isf = *flag;
    const int id = blockIdx.x + (blockIdx.y << 2);
    const int nid = (id & 7) * 256 + (id >> 3);
    const int y = nid >> 2;
    const int x = nid & 3;
    gemm_dev<8>(A, 512, Wt, bias, C, y * 128, x * 128, 0, isf, isf);
}

// ---------------------------------------------------------------------------
// Attention v4 (unchanged -- measured good): block per (bn,head);
// 4 waves x 64 query rows; flash loop over 4 key-tiles of 64; K/V double-
// buffered with prefetch; in-register P via swapped QK^T + pi-permuted V.
// ---------------------------------------------------------------------------
__global__ __launch_bounds__(256, 2) void k_attn(const uint16_t* __restrict__ qws,
                                                 const uint16_t* __restrict__ kws,
                                                 const uint16_t* __restrict__ vws,
                                                 uint16_t* __restrict__ ows) {
    // uint16 element offsets into sm (32 KB total):
    //   Kb[buf]: buf*4096            (64 rows x 8 chunks x 8, chunk-XOR swizzled)
    //   Vt[buf]: 8192 + buf*4096     (64 dims x 64 key-slots, pi-permuted + swizzled)
    __shared__ __align__(16) uint16_t sm[16384];

    const int bx = blockIdx.x;
    const int bn = bx >> 3, h = bx & 7;
    const int tid = threadIdx.x;
    const int lane = tid & 63, w = tid >> 6;
    const int quad = lane >> 4, cl = lane & 15;
    const size_t base = (size_t)bn * 256 * 512 + h * 64;
    const int qbase = w * 64;

    // Q fragments (B-operand of swapped QK; same layout as A-frag):
    // lane holds Q[qbase+mt*16+cl][ks*32+quad*8+j]
    short8 qf[4][2];
#pragma unroll
    for (int mt = 0; mt < 4; ++mt)
#pragma unroll
        for (int ks = 0; ks < 2; ++ks)
            qf[mt][ks] = *(const short8*)(qws + base + (size_t)(qbase + mt * 16 + cl) * 512 + ks * 32 + quad * 8);

    f32x4 O[4][4];
    float lsum[4];
#pragma unroll
    for (int mt = 0; mt < 4; ++mt) {
#pragma unroll
        for (int nt = 0; nt < 4; ++nt) O[mt][nt] = (f32x4){0.f, 0.f, 0.f, 0.f};
        lsum[mt] = 0.f;
    }

    short8 vreg[2];
    // ---- prologue: stage tile 0 into buffer 0 ----
    {
#pragma unroll
        for (int i = 0; i < 2; ++i) {
            const int s = i * 256 + tid;
            const int row = s >> 3;
            const int gc = (s & 7) ^ (row & 7);
            __builtin_amdgcn_global_load_lds(AS1(kws + base + (size_t)row * 512 + gc * 8),
                                             AS3(sm + (i * 256 + w * 64) * 8), 16, 0, 0);
        }
#pragma unroll
        for (int i = 0; i < 2; ++i) {
            const int it = i * 256 + tid;
            const int key = it >> 3, db = (it & 7) * 8;
            vreg[i] = *(const short8*)(vws + base + (size_t)key * 512 + db);
        }
        // V write with pi-permuted key->slot map: slot chunk c=(key>>5)*4+((key>>2)&3),
        // elem j2=((key>>4)&1)*4+(key&3); chunk XOR-swizzled by fd per d-row.
#pragma unroll
        for (int i = 0; i < 2; ++i) {
            const int it = i * 256 + tid;
            const int key = it >> 3, db = (it & 7) * 8;
            const int c = ((key >> 5) & 1) * 4 + ((key >> 2) & 3);
            const int j2 = ((key >> 4) & 1) * 4 + (key & 3);
#pragma unroll
            for (int j = 0; j < 8; ++j) {
                const int d = db + j;
                const int fd = ((d >> 3) ^ d) & 7;
                sm[8192 + d * 64 + ((c ^ fd) & 7) * 8 + j2] = (uint16_t)vreg[i][j];
            }
        }
    }
    __syncthreads();

    int cur = 0;
#pragma unroll 1
    for (int kb = 0; kb < 4; ++kb) {
        const uint16_t* const Kc = sm + cur * 4096;
        const uint16_t* const Vc = sm + 8192 + cur * 4096;
        const int nb = cur ^ 1;

        // ---- issue next tile's loads (fly under this tile's compute) ----
        if (kb < 3) {
#pragma unroll
            for (int i = 0; i < 2; ++i) {
                const int s = i * 256 + tid;
                const int row = s >> 3;
                const int gc = (s & 7) ^ (row & 7);
                __builtin_amdgcn_global_load_lds(AS1(kws + base + (size_t)((kb + 1) * 64 + row) * 512 + gc * 8),
                                                 AS3(sm + nb * 4096 + (i * 256 + w * 64) * 8), 16, 0, 0);
            }
#pragma unroll
            for (int i = 0; i < 2; ++i) {
                const int it = i * 256 + tid;
                const int key = it >> 3, db = (it & 7) * 8;
                vreg[i] = *(const short8*)(vws + base + (size_t)((kb + 1) * 64 + key) * 512 + db);
            }
        }

        // ---- compute on current tile: two key-halves of 32 ----
#pragma unroll
        for (int hf = 0; hf < 2; ++hf) {
            // K fragments for this half: global nt = hf*2 + nt2
            short8 kf[2][2];
#pragma unroll
            for (int nt2 = 0; nt2 < 2; ++nt2)
#pragma unroll
                for (int ks = 0; ks < 2; ++ks) {
                    const int row = (hf * 2 + nt2) * 16 + cl;
                    const int slot = row * 8 + ((ks * 4 + quad) ^ (row & 7));
                    kf[nt2][ks] = *(const short8*)(Kc + slot * 8);
                }
            // V fragments for this half's PV step (chunk hf*4+quad, pi order)
            short8 vf[4];
#pragma unroll
            for (int nt = 0; nt < 4; ++nt) {
                const int d = nt * 16 + cl;
                const int fd = ((d >> 3) ^ d) & 7;
                vf[nt] = *(const short8*)(Vc + d * 64 + (((hf * 4 + quad) ^ fd) & 7) * 8);
            }
#pragma unroll
            for (int mt = 0; mt < 4; ++mt) {
                // swapped QK: S2[key][q], lane holds q=cl, key=(hf*2+nt2)*16+quad*4+r
                f32x4 S0 = (f32x4){0.f, 0.f, 0.f, 0.f};
                f32x4 S1 = (f32x4){0.f, 0.f, 0.f, 0.f};
#pragma unroll
                for (int ks = 0; ks < 2; ++ks) {
                    S0 = __builtin_amdgcn_mfma_f32_16x16x32_bf16(kf[0][ks], qf[mt][ks], S0, 0, 0, 0);
                    S1 = __builtin_amdgcn_mfma_f32_16x16x32_bf16(kf[1][ks], qf[mt][ks], S1, 0, 0, 0);
                }
                // exp + pack into the PV A-fragment (pi-matched: j>>2 -> nt2, j&3 -> r)
                short8 pf;
                float ls = 0.f;
#pragma unroll
                for (int r = 0; r < 4; ++r) {
                    const float pv = __expf(S0[r] * 0.125f);
                    ls += pv;
                    pf[r] = (short)f2b(pv);
                }
#pragma unroll
                for (int r = 0; r < 4; ++r) {
                    const float pv = __expf(S1[r] * 0.125f);
                    ls += pv;
                    pf[4 + r] = (short)f2b(pv);
                }
                lsum[mt] += ls;
#pragma unroll
                for (int nt = 0; nt < 4; ++nt)
                    O[mt][nt] = __builtin_amdgcn_mfma_f32_16x16x32_bf16(pf, vf[nt], O[mt][nt], 0, 0, 0);
            }
        }

        // ---- late half of V staging: pi-permuted ds_writes into next buffer ----
        if (kb < 3) {
#pragma unroll
            for (int i = 0; i < 2; ++i) {
                const int it = i * 256 + tid;
                const int key = it >> 3, db = (it & 7) * 8;
                const int c = ((key >> 5) & 1) * 4 + ((key >> 2) & 3);
                const int j2 = ((key >> 4) & 1) * 4 + (key & 3);
#pragma unroll
                for (int j = 0; j < 8; ++j) {
                    const int d = db + j;
                    const int fd = ((d >> 3) ^ d) & 7;
                    sm[8192 + nb * 4096 + d * 64 + ((c ^ fd) & 7) * 8 + j2] = (uint16_t)vreg[i][j];
                }
            }
        }
        __syncthreads();  // next tile fully staged; everyone done reading cur
        cur = nb;
    }

    // Row-sum: lane holds the partial for q=mt*16+cl over its quad's keys;
    // combine the 4 quads (lanes cl, cl+16, cl+32, cl+48).
    float linv[4];
#pragma unroll
    for (int mt = 0; mt < 4; ++mt) {
        float v = lsum[mt];
        v += __shfl_xor(v, 16, 64);
        v += __shfl_xor(v, 32, 64);
        linv[mt] = 1.0f / v;
    }

    // Epilogue: O layout is q=mt*16+quad*4+r, d=nt*16+cl. Normalizer for row
    // quad*4+r lives at lane cl=quad*4+r (any quad). Bounce normalized bf16 O
    // through the dead K/V LDS (chunk-XOR swizzled), then stores where one
    // instruction's 64 lanes cover 8 complete 128B row-slices.
    uint16_t* const Ob = sm + w * 4096;
#pragma unroll
    for (int mt = 0; mt < 4; ++mt) {
        float ln4[4];
#pragma unroll
        for (int r = 0; r < 4; ++r) ln4[r] = __shfl(linv[mt], quad * 4 + r, 64);
#pragma unroll
        for (int nt = 0; nt < 4; ++nt)
#pragma unroll
            for (int r = 0; r < 4; ++r) {
                const int row = mt * 16 + quad * 4 + r;
                const int col = nt * 16 + cl;
                Ob[row * 64 + ((((col >> 3) ^ (row & 7)) & 7) * 8 + (col & 7))] =
                    f2b(O[mt][nt][r] * ln4[r]);
            }
    }
    // lane -> (row = g*8 + lane>>3, chunk = lane&7): full 64B lines per inst.
#pragma unroll
    for (int g = 0; g < 8; ++g) {
        const int row = g * 8 + (lane >> 3);
        const int c = lane & 7;
        const short8 ov = *(const short8*)(Ob + row * 64 + ((c ^ (row & 7)) & 7) * 8);
        *(short8*)(ows + base + (size_t)(qbase + row) * 512 + c * 8) = ov;
    }
}

// ---------------------------------------------------------------------------
extern "C" void kernel_launch(void* const* d_in, const int* in_sizes, int n_in,
                              void* d_out, int out_size, void* d_ws, size_t ws_size,
                              hipStream_t stream) {
    uint16_t* ws = (uint16_t*)d_ws;

    int* flag = (int*)d_ws;                   // 4 bytes
    uint16_t* wt_q = ws + 256;                // 512x128 bf16
    uint16_t* wt_k = wt_q + 128 * 512;
    uint16_t* wt_v = wt_k + 128 * 512;
    uint16_t* wt_o = wt_v + 128 * 512;        // 512x512 bf16
    uint16_t* q_ws = wt_o + 512 * 512;        // 65536x512 bf16; also attn out
    const size_t QKV = (size_t)65536 * 512;
    uint16_t* k_ws = q_ws + QKV;
    uint16_t* v_ws = k_ws + QKV;
    // total ws use ~193 MiB

    k_detect<<<1, 64, 0, stream>>>((const uint16_t*)d_in[0], flag);
    k_transpose<<<dim3(1024, 4), 256, 0, stream>>>(d_in[3], d_in[5], d_in[7], d_in[9],
                                                   wt_q, wt_k, wt_v, wt_o, flag);
    k_gemm_proj<<<dim3(4, 512, 3), 256, 0, stream>>>(d_in[0], d_in[1], d_in[2],
                                                     wt_q, wt_k, wt_v,
                                                     d_in[4], d_in[6], d_in[8],
                                                     q_ws, k_ws, v_ws, flag);
    k_attn<<<dim3(2048), 256, 0, stream>>>(q_ws, k_ws, v_ws, q_ws);
    k_gemm_out<<<dim3(4, 512), 256, 0, stream>>>(q_ws, wt_o, d_in[10], d_out, flag);
}

// Round 8
// 425.655 us; speedup vs baseline: 1.2645x; 1.2645x over previous
//
#include <hip/hip_runtime.h>
#include <stdint.h>
#include <stddef.h>

// B=4,N=64 -> BN=256 batches; L=256; IN=128; H=512; heads=8; hd=64.
// Inputs may be bf16 OR float32 (harness-dependent) -> runtime-detected flag.
// All internal compute: bf16 MFMA + fp32 accumulate.

typedef __attribute__((ext_vector_type(8))) short short8;
typedef __attribute__((ext_vector_type(4))) float f32x4;

#define AS1(p) ((const __attribute__((address_space(1))) void*)(p))
#define AS3(p) ((__attribute__((address_space(3))) void*)(p))

__device__ __forceinline__ float b2f(uint16_t u) {
    union { uint32_t i; float f; } x; x.i = ((uint32_t)u) << 16; return x.f;
}
__device__ __forceinline__ uint16_t f2b(float f) {
    union { float f; uint32_t i; } x; x.f = f;
    uint32_t r = x.i + 0x7fffu + ((x.i >> 16) & 1u);  // RNE
    return (uint16_t)(r >> 16);
}

// ---------------------------------------------------------------------------
// Dtype sniffer: bf16 N(0,1) data -> exponent field in ~[110,135] (outliers
// ~0%). float32 data read as uint16: even elements are f32 low-mantissa
// halves -> ~uniform exponent bits -> ~42% outliers. flag=1 means float32.
// ---------------------------------------------------------------------------
__global__ void k_detect(const uint16_t* __restrict__ q, int* __restrict__ flag) {
    const int t = threadIdx.x;
    int cnt = 0;
    for (int i = 0; i < 32; ++i) {
        const int e = (q[t * 32 + i] >> 7) & 0xff;
        cnt += (e < 110) | (e > 135);
    }
#pragma unroll
    for (int m = 1; m < 64; m <<= 1) cnt += __shfl_xor(cnt, m, 64);
    if (t == 0) *flag = (cnt > 256) ? 1 : 0;
}

__device__ __forceinline__ uint16_t rd_any(const void* p, size_t idx, int isf) {
    return isf ? f2b(((const float*)p)[idx]) : ((const uint16_t*)p)[idx];
}

// ---------------------------------------------------------------------------
// Transpose weights W (K x 512) -> Wt (512 x K) bf16, so GEMM B-fragments
// read 16B contiguous along k. Tiny, L2-resident.
// ---------------------------------------------------------------------------
__global__ void k_transpose(const void* __restrict__ Wq, const void* __restrict__ Wk,
                            const void* __restrict__ Wv, const void* __restrict__ Wo,
                            uint16_t* __restrict__ wtq, uint16_t* __restrict__ wtk,
                            uint16_t* __restrict__ wtv, uint16_t* __restrict__ wto,
                            const int* __restrict__ flag) {
    const int isf = *flag;
    const int z = blockIdx.y;
    const int t = blockIdx.x * 256 + threadIdx.x;
    if (z < 3) {
        if (t >= 128 * 512) return;
        const void* W = (z == 0) ? Wq : (z == 1) ? Wk : Wv;
        uint16_t* o = (z == 0) ? wtq : (z == 1) ? wtk : wtv;
        const int k = t & 127, n = t >> 7;
        o[t] = rd_any(W, (size_t)k * 512 + n, isf);   // o[n*128+k] = W[k][n]
    } else {
        const int k = t & 511, n = t >> 9;
        wto[t] = rd_any(Wo, (size_t)k * 512 + n, isf);
    }
}

// ---------------------------------------------------------------------------
// GEMM v8: R6 staged core + DOUBLE-BUFFERED prefetch (the attn-R1-proven
// pattern: gload_lds into buf^1 issued BEFORE compute on buf, ONE barrier
// per K-step). C(Mx512)=A(MxK)@Wt(512xK)^T + bias. 128x128 tile, BK=64,
// 4 waves 2x2, 16x16x32 bf16 MFMA, chunk-XOR LDS swizzle, XCD-swizzled grid.
//
// Session record honored:
//  * ZERO persistent staging registers across MFMA (R4/R7: spill/serialize).
//  * bf16 staging via global_load_lds only (R7: direct-fragment loses reuse).
//  * f32-A staging converts WRITE-EARLY (exposed) rather than holding 32
//    VGPRs across the MFMA cluster; B-staging is still fully hidden.
//  * 64 KB LDS -> 2 blocks/CU (known cost; prefetch must beat it — R2's
//    version of this lacked the XCD swizzle and n-fast grid, now present).
// k_gemm_out (pure bf16, KITERS=8) hides 7/8 stages; proj (KITERS=2) hides
// its B staging + step-1 A staging.
// ---------------------------------------------------------------------------
template<int KITERS>
__device__ __forceinline__ void gemm_dev(const void* __restrict__ Av, const int lda,
                                         const uint16_t* __restrict__ Wt,
                                         const void* __restrict__ biasv,
                                         void* __restrict__ Cv,
                                         const int m0, const int n0,
                                         const int isf_a, const int isf_bias, const int isf_c) {
    __shared__ __align__(16) uint16_t At[2 * 128 * 64];
    __shared__ __align__(16) uint16_t Bt[2 * 128 * 64];
    const int tid = threadIdx.x;
    const int lane = tid & 63, w = tid >> 6;
    const int wr = w >> 1, wc = w & 1;
    const int quad = lane >> 4, cl = lane & 15;

    f32x4 acc[4][4];
#pragma unroll
    for (int i = 0; i < 4; ++i)
#pragma unroll
        for (int j = 0; j < 4; ++j) acc[i][j] = (f32x4){0.f, 0.f, 0.f, 0.f};

    // Stage tile kt into buffer buf. B always via global_load_lds (async).
    // A: bf16 -> global_load_lds; f32 -> batched loads, convert, ds_write
    // (write-early: transient regs only, dead before the MFMA cluster).
    auto stage = [&](int kt, int buf) {
        const int k0 = kt * 64;
#pragma unroll
        for (int i = 0; i < 4; ++i) {
            const int s = i * 256 + tid;
            const int row = s >> 3;
            const int gc = (s & 7) ^ (row & 7);
            __builtin_amdgcn_global_load_lds(AS1(Wt + (size_t)(n0 + row) * lda + k0 + gc * 8),
                                             AS3(Bt + buf * 8192 + (size_t)(i * 256 + w * 64) * 8), 16, 0, 0);
            if (!isf_a)
                __builtin_amdgcn_global_load_lds(AS1((const uint16_t*)Av + (size_t)(m0 + row) * lda + k0 + gc * 8),
                                                 AS3(At + buf * 8192 + (size_t)(i * 256 + w * 64) * 8), 16, 0, 0);
        }
        if (isf_a) {
            f32x4 u[4][2];
#pragma unroll
            for (int i = 0; i < 4; ++i) {
                const int s = i * 256 + tid;
                const int row = s >> 3;
                const int gc = (s & 7) ^ (row & 7);
                const float* p = (const float*)Av + (size_t)(m0 + row) * lda + k0 + gc * 8;
                u[i][0] = *(const f32x4*)p;
                u[i][1] = *(const f32x4*)(p + 4);
            }
#pragma unroll
            for (int i = 0; i < 4; ++i) {
                const int s = i * 256 + tid;
                short8 tv;
#pragma unroll
                for (int j = 0; j < 4; ++j) {
                    tv[j] = (short)f2b(u[i][0][j]);
                    tv[4 + j] = (short)f2b(u[i][1][j]);
                }
                *(short8*)(At + buf * 8192 + (size_t)s * 8) = tv;
            }
        }
    };

    stage(0, 0);
    __syncthreads();

    int cur = 0;
#pragma unroll 1
    for (int kt = 0; kt < KITERS; ++kt) {
        const int nb = cur ^ 1;
        // ---- issue next tile's staging (flies under this tile's MFMA) ----
        if (kt + 1 < KITERS) stage(kt + 1, nb);
        // ---- compute on current buffer ----
        const uint16_t* const Ac = At + cur * 8192;
        const uint16_t* const Bc = Bt + cur * 8192;
#pragma unroll
        for (int ks = 0; ks < 2; ++ks) {
            short8 af[4], bf[4];
#pragma unroll
            for (int mt = 0; mt < 4; ++mt) {
                const int row = wr * 64 + mt * 16 + cl;
                const int slot = row * 8 + ((ks * 4 + quad) ^ (row & 7));
                af[mt] = *(const short8*)(Ac + slot * 8);
            }
#pragma unroll
            for (int nt = 0; nt < 4; ++nt) {
                const int row = wc * 64 + nt * 16 + cl;
                const int slot = row * 8 + ((ks * 4 + quad) ^ (row & 7));
                bf[nt] = *(const short8*)(Bc + slot * 8);
            }
#pragma unroll
            for (int mt = 0; mt < 4; ++mt)
#pragma unroll
                for (int nt = 0; nt < 4; ++nt)
                    acc[mt][nt] = __builtin_amdgcn_mfma_f32_16x16x32_bf16(af[mt], bf[nt], acc[mt][nt], 0, 0, 0);
        }
        __syncthreads();  // next buffer staged; all waves done reading cur
        cur = nb;
    }

    // Epilogue. C/D layout (m89-verified): col=lane&15, row=quad*4+reg.
    if (!isf_c) {
        // bf16 C: bounce through wave-private LDS quarter (At is dead; the
        // loop's final barrier already separated all waves' reads).
        uint16_t* const Ob = At + w * 4096;  // 64x64, chunk-XOR swizzled
#pragma unroll
        for (int nt = 0; nt < 4; ++nt) {
            const int col = nt * 16 + cl;  // wave-local col
            const float bv = isf_bias ? ((const float*)biasv)[n0 + wc * 64 + col]
                                      : b2f(((const uint16_t*)biasv)[n0 + wc * 64 + col]);
#pragma unroll
            for (int mt = 0; mt < 4; ++mt)
#pragma unroll
                for (int r = 0; r < 4; ++r) {
                    const int row = mt * 16 + quad * 4 + r;  // wave-local row
                    Ob[row * 64 + (((col >> 3) ^ (row & 7)) & 7) * 8 + (col & 7)] =
                        f2b(acc[mt][nt][r] + bv);
                }
        }
#pragma unroll
        for (int g = 0; g < 8; ++g) {
            const int row = g * 8 + (lane >> 3);
            const int c = lane & 7;
            const short8 ov = *(const short8*)(Ob + row * 64 + ((c ^ (row & 7)) & 7) * 8);
            *(short8*)((uint16_t*)Cv + (size_t)(m0 + wr * 64 + row) * 512 + n0 + wc * 64 + c * 8) = ov;
        }
    } else {
#pragma unroll
        for (int nt = 0; nt < 4; ++nt) {
            const int col = n0 + wc * 64 + nt * 16 + cl;
            const float bv = isf_bias ? ((const float*)biasv)[col] : b2f(((const uint16_t*)biasv)[col]);
#pragma unroll
            for (int mt = 0; mt < 4; ++mt)
#pragma unroll
                for (int r = 0; r < 4; ++r) {
                    const int rowg = m0 + wr * 64 + mt * 16 + quad * 4 + r;
                    ((float*)Cv)[(size_t)rowg * 512 + col] = acc[mt][nt][r] + bv;
                }
        }
    }
}

// Grid (4,512,3): 6144 blocks. Bijective XCD remap (6144%8==0, chunk=768):
// nid=(id&7)*768+(id>>3); n-tile fastest. The 4 n-siblings of one A-tile are
// consecutive nid -> same XCD (R6-verified: FETCH 188->50 MB).
__global__ __launch_bounds__(256, 2) void k_gemm_proj(
    const void* qi, const void* ki, const void* vi,
    const uint16_t* wtq, const uint16_t* wtk, const uint16_t* wtv,
    const void* bq, const void* bk, const void* bv,
    uint16_t* cq, uint16_t* ck, uint16_t* cv, const int* flag) {
    const int isf = *flag;
    const int id = blockIdx.x + (blockIdx.y << 2) + (blockIdx.z << 11);
    const int nid = (id & 7) * 768 + (id >> 3);
    const int z = nid >> 11;
    const int y = (nid >> 2) & 511;   // m-tile
    const int x = nid & 3;            // n-tile (fast)
    const void* A = (z == 0) ? qi : (z == 1) ? ki : vi;
    const uint16_t* W = (z == 0) ? wtq : (z == 1) ? wtk : wtv;
    const void* B = (z == 0) ? bq : (z == 1) ? bk : bv;
    uint16_t* C = (z == 0) ? cq : (z == 1) ? ck : cv;
    gemm_dev<2>(A, 128, W, B, C, y * 128, x * 128, isf, isf, 0);  // C bf16
}

// Grid (4,512): 2048 blocks, chunk=256.
__global__ __launch_bounds__(256, 2) void k_gemm_out(
    const uint16_t* __restrict__ A, const uint16_t* __restrict__ Wt,
    const void* __restrict__ bias, void* __restrict__ C, const int* flag) {
    const int isf = *flag;
    const int id = blockIdx.x + (blockIdx.y << 2);
    const int nid = (id & 7) * 256 + (id >> 3);
    const int y = nid >> 2;
    const int x = nid & 3;
    gemm_dev<8>(A, 512, Wt, bias, C, y * 128, x * 128, 0, isf, isf);
}

// ---------------------------------------------------------------------------
// Attention v4 (unchanged -- measured good): block per (bn,head);
// 4 waves x 64 query rows; flash loop over 4 key-tiles of 64; K/V double-
// buffered with prefetch; in-register P via swapped QK^T + pi-permuted V.
// ---------------------------------------------------------------------------
__global__ __launch_bounds__(256, 2) void k_attn(const uint16_t* __restrict__ qws,
                                                 const uint16_t* __restrict__ kws,
                                                 const uint16_t* __restrict__ vws,
                                                 uint16_t* __restrict__ ows) {
    // uint16 element offsets into sm (32 KB total):
    //   Kb[buf]: buf*4096            (64 rows x 8 chunks x 8, chunk-XOR swizzled)
    //   Vt[buf]: 8192 + buf*4096     (64 dims x 64 key-slots, pi-permuted + swizzled)
    __shared__ __align__(16) uint16_t sm[16384];

    const int bx = blockIdx.x;
    const int bn = bx >> 3, h = bx & 7;
    const int tid = threadIdx.x;
    const int lane = tid & 63, w = tid >> 6;
    const int quad = lane >> 4, cl = lane & 15;
    const size_t base = (size_t)bn * 256 * 512 + h * 64;
    const int qbase = w * 64;

    // Q fragments (B-operand of swapped QK; same layout as A-frag):
    // lane holds Q[qbase+mt*16+cl][ks*32+quad*8+j]
    short8 qf[4][2];
#pragma unroll
    for (int mt = 0; mt < 4; ++mt)
#pragma unroll
        for (int ks = 0; ks < 2; ++ks)
            qf[mt][ks] = *(const short8*)(qws + base + (size_t)(qbase + mt * 16 + cl) * 512 + ks * 32 + quad * 8);

    f32x4 O[4][4];
    float lsum[4];
#pragma unroll
    for (int mt = 0; mt < 4; ++mt) {
#pragma unroll
        for (int nt = 0; nt < 4; ++nt) O[mt][nt] = (f32x4){0.f, 0.f, 0.f, 0.f};
        lsum[mt] = 0.f;
    }

    short8 vreg[2];
    // ---- prologue: stage tile 0 into buffer 0 ----
    {
#pragma unroll
        for (int i = 0; i < 2; ++i) {
            const int s = i * 256 + tid;
            const int row = s >> 3;
            const int gc = (s & 7) ^ (row & 7);
            __builtin_amdgcn_global_load_lds(AS1(kws + base + (size_t)row * 512 + gc * 8),
                                             AS3(sm + (i * 256 + w * 64) * 8), 16, 0, 0);
        }
#pragma unroll
        for (int i = 0; i < 2; ++i) {
            const int it = i * 256 + tid;
            const int key = it >> 3, db = (it & 7) * 8;
            vreg[i] = *(const short8*)(vws + base + (size_t)key * 512 + db);
        }
        // V write with pi-permuted key->slot map: slot chunk c=(key>>5)*4+((key>>2)&3),
        // elem j2=((key>>4)&1)*4+(key&3); chunk XOR-swizzled by fd per d-row.
#pragma unroll
        for (int i = 0; i < 2; ++i) {
            const int it = i * 256 + tid;
            const int key = it >> 3, db = (it & 7) * 8;
            const int c = ((key >> 5) & 1) * 4 + ((key >> 2) & 3);
            const int j2 = ((key >> 4) & 1) * 4 + (key & 3);
#pragma unroll
            for (int j = 0; j < 8; ++j) {
                const int d = db + j;
                const int fd = ((d >> 3) ^ d) & 7;
                sm[8192 + d * 64 + ((c ^ fd) & 7) * 8 + j2] = (uint16_t)vreg[i][j];
            }
        }
    }
    __syncthreads();

    int cur = 0;
#pragma unroll 1
    for (int kb = 0; kb < 4; ++kb) {
        const uint16_t* const Kc = sm + cur * 4096;
        const uint16_t* const Vc = sm + 8192 + cur * 4096;
        const int nb = cur ^ 1;

        // ---- issue next tile's loads (fly under this tile's compute) ----
        if (kb < 3) {
#pragma unroll
            for (int i = 0; i < 2; ++i) {
                const int s = i * 256 + tid;
                const int row = s >> 3;
                const int gc = (s & 7) ^ (row & 7);
                __builtin_amdgcn_global_load_lds(AS1(kws + base + (size_t)((kb + 1) * 64 + row) * 512 + gc * 8),
                                                 AS3(sm + nb * 4096 + (i * 256 + w * 64) * 8), 16, 0, 0);
            }
#pragma unroll
            for (int i = 0; i < 2; ++i) {
                const int it = i * 256 + tid;
                const int key = it >> 3, db = (it & 7) * 8;
                vreg[i] = *(const short8*)(vws + base + (size_t)((kb + 1) * 64 + key) * 512 + db);
            }
        }

        // ---- compute on current tile: two key-halves of 32 ----
#pragma unroll
        for (int hf = 0; hf < 2; ++hf) {
            // K fragments for this half: global nt = hf*2 + nt2
            short8 kf[2][2];
#pragma unroll
            for (int nt2 = 0; nt2 < 2; ++nt2)
#pragma unroll
                for (int ks = 0; ks < 2; ++ks) {
                    const int row = (hf * 2 + nt2) * 16 + cl;
                    const int slot = row * 8 + ((ks * 4 + quad) ^ (row & 7));
                    kf[nt2][ks] = *(const short8*)(Kc + slot * 8);
                }
            // V fragments for this half's PV step (chunk hf*4+quad, pi order)
            short8 vf[4];
#pragma unroll
            for (int nt = 0; nt < 4; ++nt) {
                const int d = nt * 16 + cl;
                const int fd = ((d >> 3) ^ d) & 7;
                vf[nt] = *(const short8*)(Vc + d * 64 + (((hf * 4 + quad) ^ fd) & 7) * 8);
            }
#pragma unroll
            for (int mt = 0; mt < 4; ++mt) {
                // swapped QK: S2[key][q], lane holds q=cl, key=(hf*2+nt2)*16+quad*4+r
                f32x4 S0 = (f32x4){0.f, 0.f, 0.f, 0.f};
                f32x4 S1 = (f32x4){0.f, 0.f, 0.f, 0.f};
#pragma unroll
                for (int ks = 0; ks < 2; ++ks) {
                    S0 = __builtin_amdgcn_mfma_f32_16x16x32_bf16(kf[0][ks], qf[mt][ks], S0, 0, 0, 0);
                    S1 = __builtin_amdgcn_mfma_f32_16x16x32_bf16(kf[1][ks], qf[mt][ks], S1, 0, 0, 0);
                }
                // exp + pack into the PV A-fragment (pi-matched: j>>2 -> nt2, j&3 -> r)
                short8 pf;
                float ls = 0.f;
#pragma unroll
                for (int r = 0; r < 4; ++r) {
                    const float pv = __expf(S0[r] * 0.125f);
                    ls += pv;
                    pf[r] = (short)f2b(pv);
                }
#pragma unroll
                for (int r = 0; r < 4; ++r) {
                    const float pv = __expf(S1[r] * 0.125f);
                    ls += pv;
                    pf[4 + r] = (short)f2b(pv);
                }
                lsum[mt] += ls;
#pragma unroll
                for (int nt = 0; nt < 4; ++nt)
                    O[mt][nt] = __builtin_amdgcn_mfma_f32_16x16x32_bf16(pf, vf[nt], O[mt][nt], 0, 0, 0);
            }
        }

        // ---- late half of V staging: pi-permuted ds_writes into next buffer ----
        if (kb < 3) {
#pragma unroll
            for (int i = 0; i < 2; ++i) {
                const int it = i * 256 + tid;
                const int key = it >> 3, db = (it & 7) * 8;
                const int c = ((key >> 5) & 1) * 4 + ((key >> 2) & 3);
                const int j2 = ((key >> 4) & 1) * 4 + (key & 3);
#pragma unroll
                for (int j = 0; j < 8; ++j) {
                    const int d = db + j;
                    const int fd = ((d >> 3) ^ d) & 7;
                    sm[8192 + nb * 4096 + d * 64 + ((c ^ fd) & 7) * 8 + j2] = (uint16_t)vreg[i][j];
                }
            }
        }
        __syncthreads();  // next tile fully staged; everyone done reading cur
        cur = nb;
    }

    // Row-sum: lane holds the partial for q=mt*16+cl over its quad's keys;
    // combine the 4 quads (lanes cl, cl+16, cl+32, cl+48).
    float linv[4];
#pragma unroll
    for (int mt = 0; mt < 4; ++mt) {
        float v = lsum[mt];
        v += __shfl_xor(v, 16, 64);
        v += __shfl_xor(v, 32, 64);
        linv[mt] = 1.0f / v;
    }

    // Epilogue: O layout is q=mt*16+quad*4+r, d=nt*16+cl. Normalizer for row
    // quad*4+r lives at lane cl=quad*4+r (any quad). Bounce normalized bf16 O
    // through the dead K/V LDS (chunk-XOR swizzled), then stores where one
    // instruction's 64 lanes cover 8 complete 128B row-slices.
    uint16_t* const Ob = sm + w * 4096;
#pragma unroll
    for (int mt = 0; mt < 4; ++mt) {
        float ln4[4];
#pragma unroll
        for (int r = 0; r < 4; ++r) ln4[r] = __shfl(linv[mt], quad * 4 + r, 64);
#pragma unroll
        for (int nt = 0; nt < 4; ++nt)
#pragma unroll
            for (int r = 0; r < 4; ++r) {
                const int row = mt * 16 + quad * 4 + r;
                const int col = nt * 16 + cl;
                Ob[row * 64 + ((((col >> 3) ^ (row & 7)) & 7) * 8 + (col & 7))] =
                    f2b(O[mt][nt][r] * ln4[r]);
            }
    }
    // lane -> (row = g*8 + lane>>3, chunk = lane&7): full 64B lines per inst.
#pragma unroll
    for (int g = 0; g < 8; ++g) {
        const int row = g * 8 + (lane >> 3);
        const int c = lane & 7;
        const short8 ov = *(const short8*)(Ob + row * 64 + ((c ^ (row & 7)) & 7) * 8);
        *(short8*)(ows + base + (size_t)(qbase + row) * 512 + c * 8) = ov;
    }
}

// ---------------------------------------------------------------------------
extern "C" void kernel_launch(void* const* d_in, const int* in_sizes, int n_in,
                              void* d_out, int out_size, void* d_ws, size_t ws_size,
                              hipStream_t stream) {
    uint16_t* ws = (uint16_t*)d_ws;

    int* flag = (int*)d_ws;                   // 4 bytes
    uint16_t* wt_q = ws + 256;                // 512x128 bf16
    uint16_t* wt_k = wt_q + 128 * 512;
    uint16_t* wt_v = wt_k + 128 * 512;
    uint16_t* wt_o = wt_v + 128 * 512;        // 512x512 bf16
    uint16_t* q_ws = wt_o + 512 * 512;        // 65536x512 bf16; also attn out
    const size_t QKV = (size_t)65536 * 512;
    uint16_t* k_ws = q_ws + QKV;
    uint16_t* v_ws = k_ws + QKV;
    // total ws use ~193 MiB

    k_detect<<<1, 64, 0, stream>>>((const uint16_t*)d_in[0], flag);
    k_transpose<<<dim3(1024, 4), 256, 0, stream>>>(d_in[3], d_in[5], d_in[7], d_in[9],
                                                   wt_q, wt_k, wt_v, wt_o, flag);
    k_gemm_proj<<<dim3(4, 512, 3), 256, 0, stream>>>(d_in[0], d_in[1], d_in[2],
                                                     wt_q, wt_k, wt_v,
                                                     d_in[4], d_in[6], d_in[8],
                                                     q_ws, k_ws, v_ws, flag);
    k_attn<<<dim3(2048), 256, 0, stream>>>(q_ws, k_ws, v_ws, q_ws);
    k_gemm_out<<<dim3(4, 512), 256, 0, stream>>>(q_ws, wt_o, d_in[10], d_out, flag);
}